// Round 11
// baseline (195.630 us; speedup 1.0000x reference)
//
#include <hip/hip_runtime.h>
#include <hip/hip_bf16.h>

#define DFEAT 64
#define NBSH  8        // bucket = dst >> 8 (256 nodes per bucket)
#define NPB   256
#define EPB   4096     // edges per partition block (293 blocks)
#define EPT   (EPB / 256)
#define CAPB  3584     // per-bucket edge capacity (mean 3070 + ~9 sigma)
#define REGS  5632     // per-bucket region stride: CAPB + 8*NPB pad slots (x8 padding)
#define BSTR  32       // bcnt stride in ints: 1 counter per 128B line

typedef float f2 __attribute__((ext_vector_type(2)));

// ---- K1: one-pass bucket partition (proven R6/R7) ----
__global__ __launch_bounds__(256) void part_kernel(const int* __restrict__ ei,
                                                   int* __restrict__ bcnt,
                                                   unsigned* __restrict__ ebuf, int E) {
    __shared__ int h[512];
    __shared__ int base[512];
    int t = threadIdx.x;
    h[t] = 0; h[t + 256] = 0;
    __syncthreads();
    int bb = blockIdx.x * EPB;
    int sv[EPT], dv[EPT];
    #pragma unroll
    for (int i = 0; i < EPT; ++i) {
        int e = bb + i * 256 + t;
        if (e < E) {
            sv[i] = ei[e];
            dv[i] = ei[E + e];
            atomicAdd(&h[dv[i] >> NBSH], 1);
        } else dv[i] = -1;
    }
    __syncthreads();
    base[t]       = h[t]       ? atomicAdd(&bcnt[t * BSTR],         h[t])       : 0;
    base[t + 256] = h[t + 256] ? atomicAdd(&bcnt[(t + 256) * BSTR], h[t + 256]) : 0;
    __syncthreads();
    h[t] = 0; h[t + 256] = 0;
    __syncthreads();
    #pragma unroll
    for (int i = 0; i < EPT; ++i) {
        if (dv[i] >= 0) {
            int bkt = dv[i] >> NBSH;
            int pos = base[bkt] + atomicAdd(&h[bkt], 1);
            if (pos < CAPB)
                ebuf[(size_t)bkt * REGS + pos] =
                    (unsigned)sv[i] | ((unsigned)(dv[i] & (NPB - 1)) << 17);
        }
    }
}

// ---- K2: per-bucket CSR build IN PLACE; slots padded to x8 for uint4 gather ----
__global__ __launch_bounds__(256) void csr_kernel(const int* __restrict__ bcnt,
                                                  unsigned* __restrict__ buf,
                                                  int2* __restrict__ bl,
                                                  float* __restrict__ dinv, int n) {
    __shared__ unsigned eb[CAPB];   // 14 KB
    __shared__ int cnt[256];
    __shared__ int tmp[256];
    int t = threadIdx.x, b = blockIdx.x;
    int ecnt = bcnt[b * BSTR]; if (ecnt > CAPB) ecnt = CAPB;
    size_t rb = (size_t)b * REGS;

    const uint4* bufv = (const uint4*)(buf + rb);
    uint4* ebv = (uint4*)eb;
    int nv = (ecnt + 3) >> 2;
    for (int i = t; i < nv; i += 256) ebv[i] = bufv[i];
    cnt[t] = 0;
    __syncthreads();
    for (int i = t; i < ecnt; i += 256) atomicAdd(&cnt[eb[i] >> 17], 1);
    __syncthreads();

    int nid = (b << NBSH) + t;
    int deg = cnt[t];
    int slots = (nid < n) ? ((deg + 8) & ~7) : 0;   // >= deg+1, multiple of 8
    tmp[t] = slots;
    __syncthreads();
    int s = slots;
    for (int o = 1; o < 256; o <<= 1) {
        int y = (t >= o) ? tmp[t - o] : 0;
        __syncthreads();
        tmp[t] += y;
        __syncthreads();
    }
    int excl = tmp[t] - s;
    int beg = (int)rb + excl;
    if (nid < n) {
        bl[nid] = make_int2(beg, slots);
        dinv[nid] = rsqrtf((float)(deg + 1));
        buf[beg] = (unsigned)nid;                              // self-loop
        for (int k = deg + 1; k < slots; ++k) buf[beg + k] = (unsigned)n;  // sentinels
    }
    cnt[t] = excl + 1;                                         // cursor past self
    __syncthreads();
    for (int i = t; i < ecnt; i += 256) {
        unsigned v = eb[i];
        int pos = atomicAdd(&cnt[v >> 17], 1);
        buf[rb + pos] = v & 0x1ffffu;
    }
}

// ---- K3: xs prep (proven) ----
__global__ __launch_bounds__(256) void xsprep_kernel(const float* __restrict__ x,
                                                     const float* __restrict__ dinv,
                                                     unsigned* __restrict__ xs, int n) {
    int i = blockIdx.x * blockDim.x + threadIdx.x;
    int total = (n + 1) * 32;
    if (i >= total) return;
    int row = i >> 5, col = i & 31;
    unsigned v = 0;
    if (row < n) {
        float di = dinv[row];
        float f0 = x[(size_t)row * DFEAT + 2 * col] * di;
        float f1 = x[(size_t)row * DFEAT + 2 * col + 1] * di;
        unsigned u0 = __float_as_uint(f0); u0 = (u0 + 0x7fffu + ((u0 >> 16) & 1u)) >> 16;
        unsigned u1 = __float_as_uint(f1); u1 = (u1 + 0x7fffu + ((u1 >> 16) & 1u)) >> 16;
        v = (u0 & 0xffffu) | (u1 << 16);
    }
    xs[i] = v;
}

// ---- agg: DUAL-NODE, uint4 gather (16B/lane: half the loads+shfls),
//      pk-f32 GEMM. LDS 18.4KB -> 8 blocks/CU preserved (R10 lesson). ----
__global__ __launch_bounds__(256) void agg_kernel(const int2* __restrict__ bl,
                                                  const int* __restrict__ srcs,
                                                  const float* __restrict__ dinv,
                                                  const uint4* __restrict__ xs4,
                                                  const float* __restrict__ W,
                                                  const float* __restrict__ b,
                                                  float* __restrict__ out,
                                                  int n, int noctets) {
    __shared__ float Wl[DFEAT * DFEAT];   // 16 KB
    __shared__ float xl[8][DFEAT];        // 2 KB
    int t = threadIdx.x;
    #pragma unroll
    for (int i = 0; i < 16; ++i) Wl[i * 256 + t] = W[i * 256 + t];
    __syncthreads();   // the ONLY barrier

    int r = t >> 6, lane = t & 63;
    int g = lane >> 3;        // edge group (0..7)
    int q = lane & 7;         // uint4 column -> features 8q..8q+7
    float bias = b[lane];

    for (int oct = blockIdx.x; oct < noctets; oct += gridDim.x) {
        int na = oct * 8 + r;
        int nb_ = na + 4;
        bool va = na < n, vb = nb_ < n;
        if (!va) continue;

        int2 p0 = bl[na];
        int base0 = p0.x, end0 = p0.x + p0.y;
        int base1 = 0, end1 = 0;
        if (vb) { int2 p1 = bl[nb_]; base1 = p1.x; end1 = p1.x + p1.y; }

        float a0 = 0, a1 = 0, a2 = 0, a3 = 0, a4 = 0, a5 = 0, a6 = 0, a7 = 0;
        float c0 = 0, c1 = 0, c2 = 0, c3 = 0, c4 = 0, c5 = 0, c6 = 0, c7 = 0;
        while (base0 < end0 || base1 < end1) {
            int m0 = end0 - base0; m0 = m0 < 0 ? 0 : (m0 > 64 ? 64 : m0);
            int m1 = end1 - base1; m1 = m1 < 0 ? 0 : (m1 > 64 ? 64 : m1);
            int idx0 = 0, idx1 = 0;
            if (lane < m0) idx0 = srcs[base0 + lane];
            if (lane < m1) idx1 = srcs[base1 + lane];
            int q0 = m0 >> 3, q1 = m1 >> 3;   // slots are x8-padded: exact
            int qc = q0 < q1 ? q0 : q1;
            #pragma unroll 2
            for (int j = 0; j < qc; ++j) {
                int sv0 = __shfl(idx0, 8 * j + g, 64);
                int sv1 = __shfl(idx1, 8 * j + g, 64);
                uint4 d0 = xs4[(unsigned)sv0 * 8 + q];
                uint4 d1 = xs4[(unsigned)sv1 * 8 + q];
                a0 += __uint_as_float(d0.x << 16); a1 += __uint_as_float(d0.x & 0xffff0000u);
                a2 += __uint_as_float(d0.y << 16); a3 += __uint_as_float(d0.y & 0xffff0000u);
                a4 += __uint_as_float(d0.z << 16); a5 += __uint_as_float(d0.z & 0xffff0000u);
                a6 += __uint_as_float(d0.w << 16); a7 += __uint_as_float(d0.w & 0xffff0000u);
                c0 += __uint_as_float(d1.x << 16); c1 += __uint_as_float(d1.x & 0xffff0000u);
                c2 += __uint_as_float(d1.y << 16); c3 += __uint_as_float(d1.y & 0xffff0000u);
                c4 += __uint_as_float(d1.z << 16); c5 += __uint_as_float(d1.z & 0xffff0000u);
                c6 += __uint_as_float(d1.w << 16); c7 += __uint_as_float(d1.w & 0xffff0000u);
            }
            #pragma unroll 2
            for (int j = qc; j < q0; ++j) {
                int sv0 = __shfl(idx0, 8 * j + g, 64);
                uint4 d0 = xs4[(unsigned)sv0 * 8 + q];
                a0 += __uint_as_float(d0.x << 16); a1 += __uint_as_float(d0.x & 0xffff0000u);
                a2 += __uint_as_float(d0.y << 16); a3 += __uint_as_float(d0.y & 0xffff0000u);
                a4 += __uint_as_float(d0.z << 16); a5 += __uint_as_float(d0.z & 0xffff0000u);
                a6 += __uint_as_float(d0.w << 16); a7 += __uint_as_float(d0.w & 0xffff0000u);
            }
            #pragma unroll 2
            for (int j = qc; j < q1; ++j) {
                int sv1 = __shfl(idx1, 8 * j + g, 64);
                uint4 d1 = xs4[(unsigned)sv1 * 8 + q];
                c0 += __uint_as_float(d1.x << 16); c1 += __uint_as_float(d1.x & 0xffff0000u);
                c2 += __uint_as_float(d1.y << 16); c3 += __uint_as_float(d1.y & 0xffff0000u);
                c4 += __uint_as_float(d1.z << 16); c5 += __uint_as_float(d1.z & 0xffff0000u);
                c6 += __uint_as_float(d1.w << 16); c7 += __uint_as_float(d1.w & 0xffff0000u);
            }
            base0 += 64; base1 += 64;
        }
        // reduce across the 8 edge-groups (lanes differing in bits 3..5)
        #pragma unroll
        for (int off = 8; off < 64; off <<= 1) {
            a0 += __shfl_xor(a0, off, 64); a1 += __shfl_xor(a1, off, 64);
            a2 += __shfl_xor(a2, off, 64); a3 += __shfl_xor(a3, off, 64);
            a4 += __shfl_xor(a4, off, 64); a5 += __shfl_xor(a5, off, 64);
            a6 += __shfl_xor(a6, off, 64); a7 += __shfl_xor(a7, off, 64);
            c0 += __shfl_xor(c0, off, 64); c1 += __shfl_xor(c1, off, 64);
            c2 += __shfl_xor(c2, off, 64); c3 += __shfl_xor(c3, off, 64);
            c4 += __shfl_xor(c4, off, 64); c5 += __shfl_xor(c5, off, 64);
            c6 += __shfl_xor(c6, off, 64); c7 += __shfl_xor(c7, off, 64);
        }
        if (g == 0) {   // lanes 0..7: lane q writes features 8q..8q+7
            float dia = dinv[na];
            xl[r][8 * q + 0] = a0 * dia; xl[r][8 * q + 1] = a1 * dia;
            xl[r][8 * q + 2] = a2 * dia; xl[r][8 * q + 3] = a3 * dia;
            xl[r][8 * q + 4] = a4 * dia; xl[r][8 * q + 5] = a5 * dia;
            xl[r][8 * q + 6] = a6 * dia; xl[r][8 * q + 7] = a7 * dia;
            if (vb) {
                float dib = dinv[nb_];
                xl[r + 4][8 * q + 0] = c0 * dib; xl[r + 4][8 * q + 1] = c1 * dib;
                xl[r + 4][8 * q + 2] = c2 * dib; xl[r + 4][8 * q + 3] = c3 * dib;
                xl[r + 4][8 * q + 4] = c4 * dib; xl[r + 4][8 * q + 5] = c5 * dib;
                xl[r + 4][8 * q + 6] = c6 * dib; xl[r + 4][8 * q + 7] = c7 * dib;
            }
        }
        // wave-synchronous LDS: same wave wrote xl rows r / r+4, same wave reads.

        // GEMM with packed f32 (even/odd accumulators -> order-identical to split form)
        f2 oA; oA.x = bias; oA.y = 0.0f;
        f2 oB; oB.x = bias; oB.y = 0.0f;
        #pragma unroll
        for (int k = 0; k < DFEAT; k += 2) {
            f2 w; w.x = Wl[k * DFEAT + lane]; w.y = Wl[(k + 1) * DFEAT + lane];
            f2 xa = *(const f2*)&xl[r][k];
            f2 xb = *(const f2*)&xl[r + 4][k];
            oA += xa * w;
            oB += xb * w;
        }
        float oa = oA.x + oA.y;
        float ob = oB.x + oB.y;

        float ssa = oa * oa, ssb = ob * ob;
        #pragma unroll
        for (int off = 32; off > 0; off >>= 1) {
            ssa += __shfl_xor(ssa, off, 64);
            ssb += __shfl_xor(ssb, off, 64);
        }
        float norma = fmaxf(sqrtf(ssa), 1e-15f);
        float sca = fminf(tanhf(norma), 1.0f - 4e-3f) / norma;
        out[(long long)na * DFEAT + lane] = oa * sca;
        if (vb) {
            float normb = fmaxf(sqrtf(ssb), 1e-15f);
            float scb = fminf(tanhf(normb), 1.0f - 4e-3f) / normb;
            out[(long long)nb_ * DFEAT + lane] = ob * scb;
        }
    }
}

// ---------------- launch ----------------

extern "C" void kernel_launch(void* const* d_in, const int* in_sizes, int n_in,
                              void* d_out, int out_size, void* d_ws, size_t ws_size,
                              hipStream_t stream) {
    const float* x = (const float*)d_in[0];
    const float* W = (const float*)d_in[1];
    const float* b = (const float*)d_in[2];
    const int* ei  = (const int*)d_in[3];

    int n = in_sizes[0] / DFEAT;           // 100000
    int E = in_sizes[3] / 2;               // 1200000
    int NBUCK = (n + NPB - 1) / NPB;       // 391
    int nblk = (E + EPB - 1) / EPB;        // 293
    int noctets = (n + 7) / 8;             // 12500

    // workspace layout, ~22.9 MB total
    int* bcnt = (int*)d_ws;                               // 512*BSTR (zeroed, padded)
    unsigned* buf = (unsigned*)(bcnt + 512 * BSTR);       // NBUCK*REGS (~8.8 MB), 16B-aligned
    int2* bl = (int2*)(buf + (size_t)NBUCK * REGS);       // n
    float* dinv = (float*)(bl + n);                       // n
    size_t xsoff = (size_t)(((int*)dinv + n) - (int*)d_ws);
    xsoff = (xsoff + 31) & ~(size_t)31;                   // 128B-align
    unsigned* xs = (unsigned*)d_ws + xsoff;               // (n+1)*32

    float* out = (float*)d_out;

    int aggblocks = 2048;                  // 8 blocks/CU (LDS 18.4K)
    if (aggblocks > noctets) aggblocks = noctets;
    int xsblocks = ((n + 1) * 32 + 255) / 256;            // 12501

    hipMemsetAsync(bcnt, 0, 512 * BSTR * sizeof(int), stream);
    part_kernel  <<<nblk, 256, 0, stream>>>(ei, bcnt, buf, E);
    csr_kernel   <<<NBUCK, 256, 0, stream>>>(bcnt, buf, bl, dinv, n);
    xsprep_kernel<<<xsblocks, 256, 0, stream>>>(x, dinv, xs, n);
    agg_kernel   <<<aggblocks, 256, 0, stream>>>(bl, (const int*)buf, dinv,
                                                 (const uint4*)xs, W, b, out, n, noctets);
}

// Round 12
// 178.987 us; speedup vs baseline: 1.0930x; 1.0930x over previous
//
#include <hip/hip_runtime.h>
#include <hip/hip_bf16.h>

#define DFEAT 64
#define NBSH  8        // bucket = dst >> 8 (256 nodes per bucket)
#define NPB   256
#define EPB   4096     // edges per partition block (293 blocks)
#define EPT   (EPB / 256)
#define CAPB  3584     // per-bucket edge capacity (mean 3070 + ~9 sigma)
#define REGS  4608     // per-bucket region stride: CAPB + 4*NPB pad slots
#define BSTR  32       // bcnt stride in ints: 1 counter per 128B line

// ---- K1: one-pass bucket partition ----
// LDS bucket hist -> one global atomicAdd per non-empty bucket (padded
// counters) -> LDS-cursor scatter of packed (dst&255)<<17|src.
__global__ __launch_bounds__(256) void part_kernel(const int* __restrict__ ei,
                                                   int* __restrict__ bcnt,
                                                   unsigned* __restrict__ ebuf, int E) {
    __shared__ int h[512];
    __shared__ int base[512];
    int t = threadIdx.x;
    h[t] = 0; h[t + 256] = 0;
    __syncthreads();
    int bb = blockIdx.x * EPB;
    int sv[EPT], dv[EPT];
    #pragma unroll
    for (int i = 0; i < EPT; ++i) {
        int e = bb + i * 256 + t;
        if (e < E) {
            sv[i] = ei[e];
            dv[i] = ei[E + e];
            atomicAdd(&h[dv[i] >> NBSH], 1);
        } else dv[i] = -1;
    }
    __syncthreads();
    base[t]       = h[t]       ? atomicAdd(&bcnt[t * BSTR],         h[t])       : 0;
    base[t + 256] = h[t + 256] ? atomicAdd(&bcnt[(t + 256) * BSTR], h[t + 256]) : 0;
    __syncthreads();
    h[t] = 0; h[t + 256] = 0;
    __syncthreads();
    #pragma unroll
    for (int i = 0; i < EPT; ++i) {
        if (dv[i] >= 0) {
            int bkt = dv[i] >> NBSH;
            int pos = base[bkt] + atomicAdd(&h[bkt], 1);
            if (pos < CAPB)
                ebuf[(size_t)bkt * REGS + pos] =
                    (unsigned)sv[i] | ((unsigned)(dv[i] & (NPB - 1)) << 17);
        }
    }
}

// ---- K2: per-bucket CSR build IN PLACE (LDS-staged, LDS deg hist) ----
__global__ __launch_bounds__(256) void csr_kernel(const int* __restrict__ bcnt,
                                                  unsigned* __restrict__ buf,
                                                  int* __restrict__ begs,
                                                  int* __restrict__ lens,
                                                  float* __restrict__ dinv, int n) {
    __shared__ unsigned eb[CAPB];   // 14 KB
    __shared__ int cnt[256];
    __shared__ int tmp[256];
    int t = threadIdx.x, b = blockIdx.x;
    int ecnt = bcnt[b * BSTR]; if (ecnt > CAPB) ecnt = CAPB;
    size_t rb = (size_t)b * REGS;

    // stage packed edges to LDS, 16B vectors (region is 16B-aligned)
    const uint4* bufv = (const uint4*)(buf + rb);
    uint4* ebv = (uint4*)eb;
    int nv = (ecnt + 3) >> 2;
    for (int i = t; i < nv; i += 256) ebv[i] = bufv[i];
    cnt[t] = 0;
    __syncthreads();                                 // fences staging + cnt init
    for (int i = t; i < ecnt; i += 256) atomicAdd(&cnt[eb[i] >> 17], 1);
    __syncthreads();

    int nid = (b << NBSH) + t;
    int deg = cnt[t];
    int slots = (nid < n) ? ((deg + 4) & ~3) : 0;    // >= deg+1, multiple of 4
    tmp[t] = slots;
    __syncthreads();
    int s = slots;
    for (int o = 1; o < 256; o <<= 1) {
        int y = (t >= o) ? tmp[t - o] : 0;
        __syncthreads();
        tmp[t] += y;
        __syncthreads();
    }
    int excl = tmp[t] - s;
    int beg = (int)rb + excl;
    if (nid < n) {
        begs[nid] = beg;
        lens[nid] = slots;
        dinv[nid] = rsqrtf((float)(deg + 1));
        buf[beg] = (unsigned)nid;                              // self-loop
        for (int k = deg + 1; k < slots; ++k) buf[beg + k] = (unsigned)n;  // sentinels
    }
    cnt[t] = excl + 1;                                         // cursor past self
    __syncthreads();
    for (int i = t; i < ecnt; i += 256) {
        unsigned v = eb[i];
        int pos = atomicAdd(&cnt[v >> 17], 1);
        buf[rb + pos] = v & 0x1ffffu;
    }
}

// ---- K3: xs[row] = bf16(x[row] * dinv[row]) packed 2/dword; row n = zeros ----
__global__ __launch_bounds__(256) void xsprep_kernel(const float* __restrict__ x,
                                                     const float* __restrict__ dinv,
                                                     unsigned* __restrict__ xs, int n) {
    int i = blockIdx.x * blockDim.x + threadIdx.x;
    int total = (n + 1) * 32;
    if (i >= total) return;
    int row = i >> 5, col = i & 31;
    unsigned v = 0;
    if (row < n) {
        float di = dinv[row];
        float f0 = x[(size_t)row * DFEAT + 2 * col] * di;
        float f1 = x[(size_t)row * DFEAT + 2 * col + 1] * di;
        unsigned u0 = __float_as_uint(f0); u0 = (u0 + 0x7fffu + ((u0 >> 16) & 1u)) >> 16;
        unsigned u1 = __float_as_uint(f1); u1 = (u1 + 0x7fffu + ((u1 >> 16) & 1u)) >> 16;
        v = (u0 & 0xffffu) | (u1 << 16);
    }
    xs[i] = v;
}

// ---- Persistent fused DUAL-NODE gather -> shared GEMM(+bias) -> expmap0 -> proj ----
// (the proven 70 us configuration: dual node, uint2 gather, scalar-FMA GEMM)
__global__ __launch_bounds__(256) void agg_kernel(const int* __restrict__ begs,
                                                  const int* __restrict__ lens,
                                                  const int* __restrict__ srcs,
                                                  const float* __restrict__ dinv,
                                                  const uint2* __restrict__ xs2,
                                                  const float* __restrict__ W,
                                                  const float* __restrict__ b,
                                                  float* __restrict__ out,
                                                  int n, int noctets) {
    __shared__ float Wl[DFEAT * DFEAT];   // 16 KB
    __shared__ float xl[8][DFEAT];        // 2 KB
    int t = threadIdx.x;
    #pragma unroll
    for (int i = 0; i < 16; ++i) Wl[i * 256 + t] = W[i * 256 + t];
    __syncthreads();   // the ONLY barrier

    int r = t >> 6, lane = t & 63;
    int g = lane >> 4;        // edge group (0..3)
    int q = lane & 15;        // uint2 column -> features 4q..4q+3
    float bias = b[lane];

    for (int oct = blockIdx.x; oct < noctets; oct += gridDim.x) {
        int na = oct * 8 + r;
        int nb_ = na + 4;
        bool va = na < n, vb = nb_ < n;
        if (!va) continue;

        int beg0 = begs[na],  end0 = beg0 + lens[na];
        int beg1 = 0, end1 = 0;
        if (vb) { beg1 = begs[nb_]; end1 = beg1 + lens[nb_]; }

        float a0 = 0, a1 = 0, a2 = 0, a3 = 0;
        float b0 = 0, b1 = 0, b2 = 0, b3 = 0;
        int base0 = beg0, base1 = beg1;
        while (base0 < end0 || base1 < end1) {
            int m0 = end0 - base0; m0 = m0 < 0 ? 0 : (m0 > 64 ? 64 : m0);
            int m1 = end1 - base1; m1 = m1 < 0 ? 0 : (m1 > 64 ? 64 : m1);
            int idx0 = 0, idx1 = 0;
            if (lane < m0) idx0 = srcs[base0 + lane];
            if (lane < m1) idx1 = srcs[base1 + lane];
            int q0 = m0 >> 2, q1 = m1 >> 2;
            int qc = q0 < q1 ? q0 : q1;
            #pragma unroll 4
            for (int j = 0; j < qc; ++j) {
                int sv0 = __shfl(idx0, 4 * j + g, 64);
                int sv1 = __shfl(idx1, 4 * j + g, 64);
                uint2 d0 = xs2[(unsigned)sv0 * 16 + q];
                uint2 d1 = xs2[(unsigned)sv1 * 16 + q];
                a0 += __uint_as_float(d0.x << 16);
                a1 += __uint_as_float(d0.x & 0xffff0000u);
                a2 += __uint_as_float(d0.y << 16);
                a3 += __uint_as_float(d0.y & 0xffff0000u);
                b0 += __uint_as_float(d1.x << 16);
                b1 += __uint_as_float(d1.x & 0xffff0000u);
                b2 += __uint_as_float(d1.y << 16);
                b3 += __uint_as_float(d1.y & 0xffff0000u);
            }
            #pragma unroll 4
            for (int j = qc; j < q0; ++j) {
                int sv0 = __shfl(idx0, 4 * j + g, 64);
                uint2 d0 = xs2[(unsigned)sv0 * 16 + q];
                a0 += __uint_as_float(d0.x << 16);
                a1 += __uint_as_float(d0.x & 0xffff0000u);
                a2 += __uint_as_float(d0.y << 16);
                a3 += __uint_as_float(d0.y & 0xffff0000u);
            }
            #pragma unroll 4
            for (int j = qc; j < q1; ++j) {
                int sv1 = __shfl(idx1, 4 * j + g, 64);
                uint2 d1 = xs2[(unsigned)sv1 * 16 + q];
                b0 += __uint_as_float(d1.x << 16);
                b1 += __uint_as_float(d1.x & 0xffff0000u);
                b2 += __uint_as_float(d1.y << 16);
                b3 += __uint_as_float(d1.y & 0xffff0000u);
            }
            base0 += 64; base1 += 64;
        }
        #pragma unroll
        for (int off = 16; off < 64; off <<= 1) {
            a0 += __shfl_xor(a0, off, 64);
            a1 += __shfl_xor(a1, off, 64);
            a2 += __shfl_xor(a2, off, 64);
            a3 += __shfl_xor(a3, off, 64);
            b0 += __shfl_xor(b0, off, 64);
            b1 += __shfl_xor(b1, off, 64);
            b2 += __shfl_xor(b2, off, 64);
            b3 += __shfl_xor(b3, off, 64);
        }
        if (g == 0) {
            float dia = dinv[na];
            xl[r][4 * q + 0] = a0 * dia;
            xl[r][4 * q + 1] = a1 * dia;
            xl[r][4 * q + 2] = a2 * dia;
            xl[r][4 * q + 3] = a3 * dia;
            if (vb) {
                float dib = dinv[nb_];
                xl[r + 4][4 * q + 0] = b0 * dib;
                xl[r + 4][4 * q + 1] = b1 * dib;
                xl[r + 4][4 * q + 2] = b2 * dib;
                xl[r + 4][4 * q + 3] = b3 * dib;
            }
        }
        // wave-synchronous LDS: same wave wrote xl rows r / r+4, same wave reads.

        float oa0 = bias, oa1 = 0.0f, ob0 = bias, ob1 = 0.0f;
        #pragma unroll
        for (int k = 0; k < DFEAT; k += 2) {
            float w0 = Wl[k * DFEAT + lane];
            float w1 = Wl[(k + 1) * DFEAT + lane];
            oa0 = fmaf(xl[r][k],     w0, oa0);
            oa1 = fmaf(xl[r][k + 1], w1, oa1);
            ob0 = fmaf(xl[r + 4][k],     w0, ob0);
            ob1 = fmaf(xl[r + 4][k + 1], w1, ob1);
        }
        float oa = oa0 + oa1;
        float ob = ob0 + ob1;

        float ssa = oa * oa, ssb = ob * ob;
        #pragma unroll
        for (int off = 32; off > 0; off >>= 1) {
            ssa += __shfl_xor(ssa, off, 64);
            ssb += __shfl_xor(ssb, off, 64);
        }
        float norma = fmaxf(sqrtf(ssa), 1e-15f);
        float sca = fminf(tanhf(norma), 1.0f - 4e-3f) / norma;
        out[(long long)na * DFEAT + lane] = oa * sca;
        if (vb) {
            float normb = fmaxf(sqrtf(ssb), 1e-15f);
            float scb = fminf(tanhf(normb), 1.0f - 4e-3f) / normb;
            out[(long long)nb_ * DFEAT + lane] = ob * scb;
        }
    }
}

// ---------------- launch ----------------

extern "C" void kernel_launch(void* const* d_in, const int* in_sizes, int n_in,
                              void* d_out, int out_size, void* d_ws, size_t ws_size,
                              hipStream_t stream) {
    const float* x = (const float*)d_in[0];
    const float* W = (const float*)d_in[1];
    const float* b = (const float*)d_in[2];
    const int* ei  = (const int*)d_in[3];

    int n = in_sizes[0] / DFEAT;           // 100000
    int E = in_sizes[3] / 2;               // 1200000
    int NBUCK = (n + NPB - 1) / NPB;       // 391
    int nblk = (E + EPB - 1) / EPB;        // 293
    int noctets = (n + 7) / 8;             // 12500

    // workspace layout, ~21.3 MB total
    int* bcnt = (int*)d_ws;                               // 512*BSTR (zeroed, padded)
    unsigned* buf = (unsigned*)(bcnt + 512 * BSTR);       // NBUCK*REGS (~7.2 MB), 16B-aligned
    int* begs = (int*)(buf + (size_t)NBUCK * REGS);       // n
    int* lens = begs + n;                                 // n
    float* dinv = (float*)(lens + n);                     // n
    size_t xsoff = (size_t)(((int*)dinv + n) - (int*)d_ws);
    xsoff = (xsoff + 31) & ~(size_t)31;                   // 128B-align
    unsigned* xs = (unsigned*)d_ws + xsoff;               // (n+1)*32

    float* out = (float*)d_out;

    int aggblocks = 2048;                  // 8 blocks/CU (LDS 18.4K)
    if (aggblocks > noctets) aggblocks = noctets;
    int xsblocks = ((n + 1) * 32 + 255) / 256;            // 12501

    hipMemsetAsync(bcnt, 0, 512 * BSTR * sizeof(int), stream);
    part_kernel  <<<nblk, 256, 0, stream>>>(ei, bcnt, buf, E);
    csr_kernel   <<<NBUCK, 256, 0, stream>>>(bcnt, buf, begs, lens, dinv, n);
    xsprep_kernel<<<xsblocks, 256, 0, stream>>>(x, dinv, xs, n);
    agg_kernel   <<<aggblocks, 256, 0, stream>>>(begs, lens, (const int*)buf, dinv,
                                                 (const uint2*)xs, W, b, out, n, noctets);
}